// Round 7
// baseline (620.254 us; speedup 1.0000x reference)
//
#include <hip/hip_runtime.h>
#include <hip/hip_cooperative_groups.h>

// GraphUnetPool as ONE cooperative kernel (grid-stride phases, block count from
// occupancy query), with a multi-kernel fallback if coop launch is refused.

namespace cg = cooperative_groups;
typedef unsigned long long u64;
typedef unsigned int u32;

struct P {
    const float* h; const int* ei0; const int* ei1; const int* batch;
    const float* pw; const float* pb;
    u64* keys; int* rankcnt; int* deg; int* idx_list; float* vals; int* rank;
    int* offs; int* cursor; int* off2; int* len2; int* nbrrank;
    float* out_newh; float* out_ung; float* out_ea; float* out_nb; float* out_idx;
    int N; int E; int kN;
};

__global__ __launch_bounds__(256, 4) void unet_pool_all(P p) {
    extern __shared__ char smem[];
    cg::grid_group grid = cg::this_grid();
    const int b = blockIdx.x, t = threadIdx.x;
    const int NB = gridDim.x;
    const int N = p.N, E = p.E, kN = p.kN;

    // ---- Phase A: scores (1 wave/row) + zero rankcnt/deg + edge_attr ones ----
    for (int g = b * 256 + t; g < N * 64; g += NB * 256) {
        if (g < 2 * N) p.rankcnt[g] = 0;                    // rankcnt + deg (adjacent)
        if (g < (E >> 2)) ((float4*)p.out_ea)[g] = make_float4(1.f, 1.f, 1.f, 1.f);
        int wave = g >> 6, lane = t & 63;                   // g&63 == t&63 (stride %64==0)
        float4 a = ((const float4*)(p.h + (size_t)wave * 256))[lane];
        float4 c = ((const float4*)p.pw)[lane];
        float s = a.x * c.x + a.y * c.y + a.z * c.z + a.w * c.w;
        #pragma unroll
        for (int off = 32; off; off >>= 1) s += __shfl_xor(s, off);
        if (lane == 0) {
            s += p.pb[0];
            float sc = 1.0f / (1.0f + expf(-s));
            p.keys[wave] = ((u64)__float_as_uint(sc) << 32) | (u32)(~wave);
        }
    }
    grid.sync();

    // ---- Phase B: rank count (vb<1024: 256-key LDS tiles) + degree hist ----
    {
        u64* lk = (u64*)smem;
        int nvb = 1024 + (E >> 8);
        for (int vb = b; vb < nvb; vb += NB) {              // block-uniform branch
            if (vb < 1024) {
                int chunk = vb >> 5, elg = vb & 31;         // 32 chunks x 32 groups
                lk[t] = p.keys[(chunk << 8) + t];
                __syncthreads();
                int el = (elg << 8) + t;
                u64 mk = p.keys[el];
                int cnt = 0;
                #pragma unroll 16
                for (int i = 0; i < 256; ++i) cnt += (lk[i] > mk) ? 1 : 0;
                atomicAdd(&p.rankcnt[el], cnt);
                __syncthreads();                            // protect lk reuse
            } else {
                int e = ((vb - 1024) << 8) + t;
                if (e < E) atomicAdd(&p.deg[p.ei0[e]], 1);
            }
        }
    }
    grid.sync();

    // ---- Phase C: block 0 = exclusive scan; blocks 1.. = select ----
    if (b == 0) {
        int* sdata = (int*)smem;
        int per = N >> 8;                                   // 32 per thread
        int base = t * per;
        int s = 0;
        for (int j = 0; j < per; ++j) s += p.deg[base + j];
        sdata[t] = s;
        __syncthreads();
        for (int d = 1; d < 256; d <<= 1) {
            int v = (t >= d) ? sdata[t - d] : 0;
            __syncthreads();
            sdata[t] += v;
            __syncthreads();
        }
        int run = (t == 0) ? 0 : sdata[t - 1];
        for (int j = 0; j < per; ++j) {
            int dv = p.deg[base + j];
            p.offs[base + j] = run; p.cursor[base + j] = run;
            run += dv;
        }
        if (t == 255) p.offs[N] = sdata[255];
    } else {
        for (int i = (b - 1) * 256 + t; i < N; i += (NB - 1) * 256) {
            int r = p.rankcnt[i];
            p.rank[i] = (r < kN) ? r : kN;                  // kN = discard slot
            if (r < kN) {
                p.idx_list[r] = i;
                p.vals[r] = __uint_as_float((u32)(p.keys[i] >> 32));
                p.out_idx[r] = (float)i;
                p.out_nb[r] = (float)p.batch[i];
            }
        }
    }
    grid.sync();

    // ---- Phase D: new_h (vb<kN/4) + scatter w/ 2-hop descriptors ----
    {
        int nnewh = kN >> 2;
        int nvb = nnewh + (E >> 8);
        for (int vb = b; vb < nvb; vb += NB) {
            if (vb < nnewh) {
                int wave = (vb << 2) + (t >> 6), lane = t & 63;
                int i = p.idx_list[wave];
                float v = p.vals[wave];
                float4 a = ((const float4*)(p.h + (size_t)i * 256))[lane];
                ((float4*)(p.out_newh + (size_t)wave * 256))[lane] =
                    make_float4(a.x * v, a.y * v, a.z * v, a.w * v);
            } else {
                int e = ((vb - nnewh) << 8) + t;
                if (e < E) {
                    int u = p.ei0[e], v = p.ei1[e];
                    int pos = atomicAdd(&p.cursor[u], 1);
                    p.off2[pos] = p.offs[v];
                    p.len2[pos] = p.deg[v];
                    p.nbrrank[pos] = p.rank[v];
                }
            }
        }
    }
    grid.sync();

    // ---- Phase E: per-row 2-path accumulation; rows grid-stride ----
    {
        float* row = (float*)smem;                          // kN+1 floats
        int* toff = (int*)(row + kN + 1);
        int* tlen = toff + 256;
        int hw = t >> 5, hl = t & 31;
        for (int r = b; r < kN; r += NB) {
            for (int i = t; i < kN + 1; i += 256) row[i] = 0.f;
            __syncthreads();
            int u = p.idx_list[r];
            int s0 = p.offs[u], s1 = p.offs[u + 1];
            int nf = s1 - s0;
            for (int fb = 0; fb < nf; fb += 256) {
                int nt = min(256, nf - fb);
                if (t < nt) { toff[t] = p.off2[s0 + fb + t]; tlen[t] = p.len2[s0 + fb + t]; }
                __syncthreads();
                for (int f = hw; f < nt; f += 8) {
                    int t0 = toff[f], L = tlen[f];
                    for (int q = hl; q < L; q += 32)
                        atomicAdd(&row[p.nbrrank[t0 + q]], 1.0f);
                }
                __syncthreads();
            }
            float4* dst = (float4*)(p.out_ung + (size_t)r * kN);
            const float4* src = (const float4*)row;
            for (int i = t; i < (kN >> 2); i += 256) dst[i] = src[i];
            __syncthreads();
        }
    }
}

// ================= fallback path (R5, proven correct at 97 µs) =================

__global__ void fused_scores(const float* __restrict__ h, const float* __restrict__ w,
                             const float* __restrict__ b, u64* __restrict__ keys,
                             int* __restrict__ zerobuf, float4* __restrict__ ones4,
                             int N, int n4) {
    int g = blockIdx.x * blockDim.x + threadIdx.x;
    if (g < 2 * N) zerobuf[g] = 0;
    if (g < n4) ones4[g] = make_float4(1.f, 1.f, 1.f, 1.f);
    int wave = g >> 6;
    int lane = threadIdx.x & 63;
    if (wave >= N) return;
    const float4 a = ((const float4*)(h + (size_t)wave * 256))[lane];
    const float4 c = ((const float4*)w)[lane];
    float s = a.x * c.x + a.y * c.y + a.z * c.z + a.w * c.w;
    #pragma unroll
    for (int off = 32; off; off >>= 1) s += __shfl_xor(s, off);
    if (lane == 0) {
        s += b[0];
        float sc = 1.0f / (1.0f + expf(-s));
        keys[wave] = ((u64)__float_as_uint(sc) << 32) | (u32)(~wave);
    }
}

__global__ void rank_hist(const u64* __restrict__ keys, int* __restrict__ rankcnt,
                          const int* __restrict__ ei0, int* __restrict__ deg,
                          int N, int E, int nrank) {
    __shared__ u64 lk[1024];
    int b = blockIdx.x, tid = threadIdx.x;
    if (b < nrank) {
        int ngroups = N >> 8;
        int chunk = b / ngroups;
        int elg = b % ngroups;
        int base = chunk << 10;
        #pragma unroll
        for (int j = 0; j < 4; ++j) lk[tid + (j << 8)] = keys[base + tid + (j << 8)];
        __syncthreads();
        int el = (elg << 8) + tid;
        u64 mk = keys[el];
        int cnt = 0;
        #pragma unroll 16
        for (int i = 0; i < 1024; ++i) cnt += (lk[i] > mk) ? 1 : 0;
        atomicAdd(&rankcnt[el], cnt);
    } else {
        int e0 = ((b - nrank) << 10) + tid;
        #pragma unroll
        for (int j = 0; j < 4; ++j) {
            int e = e0 + (j << 8);
            if (e < E) atomicAdd(&deg[ei0[e]], 1);
        }
    }
}

__global__ void select_scan(const u64* __restrict__ keys, const int* __restrict__ rankcnt,
                            const int* __restrict__ batch, int* __restrict__ idx_list,
                            float* __restrict__ val_list, int* __restrict__ rank,
                            float* __restrict__ out_idx, float* __restrict__ out_batch,
                            const int* __restrict__ deg, int* __restrict__ offs,
                            int* __restrict__ cursor, int N, int kN) {
    __shared__ int part[1024];
    int b = blockIdx.x, t = threadIdx.x;
    int nsel = N >> 10;
    if (b < nsel) {
        int i = (b << 10) + t;
        int r = rankcnt[i];
        rank[i] = (r < kN) ? r : kN;
        if (r < kN) {
            idx_list[r] = i;
            val_list[r] = __uint_as_float((u32)(keys[i] >> 32));
            out_idx[r] = (float)i;
            out_batch[r] = (float)batch[i];
        }
    } else {
        int per = N >> 10;
        int base = t * per;
        int loc[8];
        int s = 0;
        #pragma unroll
        for (int j = 0; j < 8; ++j) { if (j < per) { loc[j] = s; s += deg[base + j]; } }
        part[t] = s;
        __syncthreads();
        for (int d = 1; d < 1024; d <<= 1) {
            int v = (t >= d) ? part[t - d] : 0;
            __syncthreads();
            part[t] += v;
            __syncthreads();
        }
        int excl = (t == 0) ? 0 : part[t - 1];
        #pragma unroll
        for (int j = 0; j < 8; ++j) {
            if (j < per) { int o = excl + loc[j]; offs[base + j] = o; cursor[base + j] = o; }
        }
        if (t == 1023) offs[N] = part[1023];
    }
}

__global__ void newh_scatter(const float* __restrict__ h, const int* __restrict__ idx_list,
                             const float* __restrict__ val_list, float* __restrict__ out_newh,
                             const int* __restrict__ ei0, const int* __restrict__ ei1,
                             int* __restrict__ cursor, const int* __restrict__ offs,
                             const int* __restrict__ deg, const int* __restrict__ rank,
                             int* __restrict__ off2, int* __restrict__ len2,
                             int* __restrict__ nbrrank, int kN, int E) {
    int b = blockIdx.x, tid = threadIdx.x;
    int nnewh = kN >> 2;
    if (b < nnewh) {
        int wave = (b << 2) + (tid >> 6);
        int lane = tid & 63;
        int i = idx_list[wave];
        float v = val_list[wave];
        float4 a = ((const float4*)(h + (size_t)i * 256))[lane];
        ((float4*)(out_newh + (size_t)wave * 256))[lane] =
            make_float4(a.x * v, a.y * v, a.z * v, a.w * v);
    } else {
        int e = ((b - nnewh) << 8) + tid;
        if (e < E) {
            int u = ei0[e], v = ei1[e];
            int p = atomicAdd(&cursor[u], 1);
            off2[p] = offs[v];
            len2[p] = deg[v];
            nbrrank[p] = rank[v];
        }
    }
}

__global__ void paths_row_kernel(const int* __restrict__ idx_list, const int* __restrict__ offs,
                                 const int* __restrict__ off2, const int* __restrict__ len2,
                                 const int* __restrict__ nbrrank, float* __restrict__ ung,
                                 int kN) {
    extern __shared__ float row[];
    int* toff = (int*)(row + kN + 1);
    int* tlen = toff + 256;
    int tid = threadIdx.x;
    for (int i = tid; i < kN + 1; i += 256) row[i] = 0.f;
    __syncthreads();
    int u = idx_list[blockIdx.x];
    int s0 = offs[u], s1 = offs[u + 1];
    int nf = s1 - s0;
    int hw = tid >> 5;
    int hl = tid & 31;
    for (int fb = 0; fb < nf; fb += 256) {
        int nt = min(256, nf - fb);
        if (tid < nt) { toff[tid] = off2[s0 + fb + tid]; tlen[tid] = len2[s0 + fb + tid]; }
        __syncthreads();
        for (int f = hw; f < nt; f += 8) {
            int t0 = toff[f], L = tlen[f];
            for (int q = hl; q < L; q += 32)
                atomicAdd(&row[nbrrank[t0 + q]], 1.0f);
        }
        __syncthreads();
    }
    float4* dst = (float4*)(ung + (size_t)blockIdx.x * kN);
    const float4* src = (const float4*)row;
    for (int i = tid; i < (kN >> 2); i += 256) dst[i] = src[i];
}

extern "C" void kernel_launch(void* const* d_in, const int* in_sizes, int n_in,
                              void* d_out, int out_size, void* d_ws, size_t ws_size,
                              hipStream_t stream) {
    const float* h = (const float*)d_in[0];
    const int* ei = (const int*)d_in[1];            // [2,E] flat
    const int* batch = (const int*)d_in[3];
    const float* pw = (const float*)d_in[4];
    const float* pb = (const float*)d_in[5];

    int N = in_sizes[3];        // 8192
    int E = in_sizes[1] / 2;    // 262144
    int kN = N / 2;
    if (kN < 2) kN = 2;

    float* out = (float*)d_out;
    float* out_newh = out;                              // kN*256
    float* out_ung = out_newh + (size_t)kN * 256;       // kN*kN
    float* out_ea = out_ung + (size_t)kN * kN;          // E
    float* out_nb = out_ea + E;                         // kN
    float* out_idx = out_nb + kN;                       // kN

    char* ws = (char*)d_ws;
    P p;
    p.h = h; p.ei0 = ei; p.ei1 = ei + E; p.batch = batch; p.pw = pw; p.pb = pb;
    p.keys    = (u64*)(ws + 0);          // 64 KB
    p.rankcnt = (int*)(ws + 65536);      // 32 KB \ zeroed in phase A
    p.deg     = (int*)(ws + 98304);      // 32 KB /
    p.idx_list= (int*)(ws + 131072);     // 16 KB
    p.vals    = (float*)(ws + 147456);   // 16 KB
    p.rank    = (int*)(ws + 163840);     // 32 KB
    p.offs    = (int*)(ws + 196608);     // 32 KB + 4
    p.cursor  = (int*)(ws + 229632);     // 32 KB
    p.off2    = (int*)(ws + 262400);     // 1 MB
    p.len2    = (int*)(ws + 1310976);    // 1 MB
    p.nbrrank = (int*)(ws + 2359552);    // 1 MB
    p.out_newh = out_newh; p.out_ung = out_ung; p.out_ea = out_ea;
    p.out_nb = out_nb; p.out_idx = out_idx;
    p.N = N; p.E = E; p.kN = kN;

    size_t shmem = (size_t)(kN + 1) * 4 + 2048;         // 18436 B

    // Query the runtime's actual co-residency and launch exactly that.
    int maxb = 0, cu = 0, dev = 0;
    hipError_t qerr = hipGetDevice(&dev);
    if (qerr == hipSuccess)
        qerr = hipDeviceGetAttribute(&cu, hipDeviceAttributeMultiprocessorCount, dev);
    if (qerr == hipSuccess)
        qerr = hipOccupancyMaxActiveBlocksPerMultiprocessor(&maxb, unet_pool_all, 256, shmem);

    hipError_t lerr = hipErrorUnknown;
    if (qerr == hipSuccess && maxb > 0 && cu > 0) {
        int nb = maxb * cu;
        if (nb > 2048) nb = 2048;
        if (nb < 2) nb = 2;                             // phase C needs >=2 blocks
        void* args[] = { &p };
        lerr = hipLaunchCooperativeKernel((const void*)unet_pool_all, dim3(nb), dim3(256),
                                          args, (unsigned)shmem, stream);
    }
    if (lerr == hipSuccess) return;

    // ---- fallback: proven 5-kernel path ----
    fused_scores<<<(N * 64 + 255) / 256, 256, 0, stream>>>(h, pw, pb, p.keys, p.rankcnt,
                                                           (float4*)out_ea, N, E / 4);
    int nrank = (N >> 10) * (N >> 8);
    int nhist = (E + 1023) / 1024;
    rank_hist<<<nrank + nhist, 256, 0, stream>>>(p.keys, p.rankcnt, ei, p.deg, N, E, nrank);
    select_scan<<<(N >> 10) + 1, 1024, 0, stream>>>(p.keys, p.rankcnt, batch, p.idx_list,
                                                    p.vals, p.rank, out_idx, out_nb, p.deg,
                                                    p.offs, p.cursor, N, kN);
    newh_scatter<<<(kN >> 2) + (E >> 8), 256, 0, stream>>>(h, p.idx_list, p.vals, out_newh,
                                                           ei, ei + E, p.cursor, p.offs,
                                                           p.deg, p.rank, p.off2, p.len2,
                                                           p.nbrrank, kN, E);
    paths_row_kernel<<<kN, 256, (kN + 1) * 4 + 2048, stream>>>(p.idx_list, p.offs, p.off2,
                                                               p.len2, p.nbrrank, out_ung, kN);
}

// Round 8
// 107.730 us; speedup vs baseline: 5.7575x; 5.7575x over previous
//
#include <hip/hip_runtime.h>

// GraphUnetPool: scores = sigmoid(h@w+b); top-k (k=N/2) by exact rank-count;
// new_h = h[idx]*values; un_g = (g@g)[idx][:,idx] via per-row LDS 2-path counting.
// 5 graph nodes: [scores+zero+ones] -> [rank+hist] -> [select+scan] ->
//                [newh+scatter+2hop-desc] -> [paths].

typedef unsigned long long u64;
typedef unsigned int u32;

// ---- node1: scores (1 wave/row) + zero rankcnt/deg + edge_attr ones ----
__global__ void fused_scores(const float* __restrict__ h, const float* __restrict__ w,
                             const float* __restrict__ b, u64* __restrict__ keys,
                             int* __restrict__ zerobuf, float4* __restrict__ ones4,
                             int N, int n4) {
    int g = blockIdx.x * blockDim.x + threadIdx.x;
    if (g < 2 * N) zerobuf[g] = 0;              // rankcnt (N) + deg (N), adjacent
    if (g < n4) ones4[g] = make_float4(1.f, 1.f, 1.f, 1.f);
    int wave = g >> 6;
    int lane = threadIdx.x & 63;
    if (wave >= N) return;
    const float4 a = ((const float4*)(h + (size_t)wave * 256))[lane];
    const float4 c = ((const float4*)w)[lane];
    float s = a.x * c.x + a.y * c.y + a.z * c.z + a.w * c.w;
    #pragma unroll
    for (int off = 32; off; off >>= 1) s += __shfl_xor(s, off);
    if (lane == 0) {
        s += b[0];
        float sc = 1.0f / (1.0f + expf(-s));
        keys[wave] = ((u64)__float_as_uint(sc) << 32) | (u32)(~wave);  // ties: lower idx
    }
}

// ---- node2: rank (4 elements/thread vs 1024-key LDS tile) + degree hist ----
__global__ void rank_hist(const u64* __restrict__ keys, int* __restrict__ rankcnt,
                          const int* __restrict__ ei0, int* __restrict__ deg,
                          int N, int E, int nrank) {
    __shared__ u64 lk[1024];
    int b = blockIdx.x, tid = threadIdx.x;
    if (b < nrank) {
        int ngroups = N >> 10;                  // element groups of 1024
        int chunk = b / ngroups;                // 1024-key chunks
        int elg = b % ngroups;
        int base = chunk << 10;
        #pragma unroll
        for (int j = 0; j < 4; ++j) lk[tid + (j << 8)] = keys[base + tid + (j << 8)];
        __syncthreads();
        int el = (elg << 10) + tid;             // 4 elements: el + k*256
        u64 mk0 = keys[el], mk1 = keys[el + 256], mk2 = keys[el + 512], mk3 = keys[el + 768];
        int c0 = 0, c1 = 0, c2 = 0, c3 = 0;
        #pragma unroll 8
        for (int i = 0; i < 1024; ++i) {
            u64 kv = lk[i];
            c0 += (kv > mk0) ? 1 : 0;
            c1 += (kv > mk1) ? 1 : 0;
            c2 += (kv > mk2) ? 1 : 0;
            c3 += (kv > mk3) ? 1 : 0;
        }
        atomicAdd(&rankcnt[el], c0);
        atomicAdd(&rankcnt[el + 256], c1);
        atomicAdd(&rankcnt[el + 512], c2);
        atomicAdd(&rankcnt[el + 768], c3);
    } else {
        int e0 = ((b - nrank) << 10) + tid;     // 4 edges/thread
        #pragma unroll
        for (int j = 0; j < 4; ++j) {
            int e = e0 + (j << 8);
            if (e < E) atomicAdd(&deg[ei0[e]], 1);
        }
    }
}

// ---- node3: select (rank scatter, outputs idx/batch) + CSR exclusive scan ----
__global__ void select_scan(const u64* __restrict__ keys, const int* __restrict__ rankcnt,
                            const int* __restrict__ batch, int* __restrict__ idx_list,
                            float* __restrict__ val_list, int* __restrict__ rank,
                            float* __restrict__ out_idx, float* __restrict__ out_batch,
                            const int* __restrict__ deg, int* __restrict__ offs,
                            int* __restrict__ cursor, int N, int kN) {
    __shared__ int part[1024];
    int b = blockIdx.x, t = threadIdx.x;
    int nsel = N >> 10;                         // select blocks (1024 thr each)
    if (b < nsel) {
        int i = (b << 10) + t;
        int r = rankcnt[i];
        rank[i] = (r < kN) ? r : kN;            // kN = discard slot
        if (r < kN) {
            idx_list[r] = i;
            val_list[r] = __uint_as_float((u32)(keys[i] >> 32));
            out_idx[r] = (float)i;
            out_batch[r] = (float)batch[i];
        }
    } else {
        int per = N >> 10;                      // 8 per thread
        int base = t * per;
        int loc[8];
        int s = 0;
        #pragma unroll
        for (int j = 0; j < 8; ++j) { if (j < per) { loc[j] = s; s += deg[base + j]; } }
        part[t] = s;
        __syncthreads();
        for (int d = 1; d < 1024; d <<= 1) {
            int v = (t >= d) ? part[t - d] : 0;
            __syncthreads();
            part[t] += v;
            __syncthreads();
        }
        int excl = (t == 0) ? 0 : part[t - 1];
        #pragma unroll
        for (int j = 0; j < 8; ++j) {
            if (j < per) { int o = excl + loc[j]; offs[base + j] = o; cursor[base + j] = o; }
        }
        if (t == 1023) offs[N] = part[1023];
    }
}

// ---- node4: new_h + scatter with packed 2-hop descriptors ----
// Slot p (edge u->v): desc[p] = {offs[v], deg[v]}, nbrrank[p] = rank[v].
__global__ void newh_scatter(const float* __restrict__ h, const int* __restrict__ idx_list,
                             const float* __restrict__ val_list, float* __restrict__ out_newh,
                             const int* __restrict__ ei0, const int* __restrict__ ei1,
                             int* __restrict__ cursor, const int* __restrict__ offs,
                             const int* __restrict__ deg, const int* __restrict__ rank,
                             int2* __restrict__ desc, int* __restrict__ nbrrank,
                             int kN, int E) {
    int b = blockIdx.x, tid = threadIdx.x;
    int nnewh = kN >> 2;                        // 4 waves/block
    if (b < nnewh) {
        int wave = (b << 2) + (tid >> 6);
        int lane = tid & 63;
        int i = idx_list[wave];
        float v = val_list[wave];
        float4 a = ((const float4*)(h + (size_t)i * 256))[lane];
        ((float4*)(out_newh + (size_t)wave * 256))[lane] =
            make_float4(a.x * v, a.y * v, a.z * v, a.w * v);
    } else {
        int e = ((b - nnewh) << 8) + tid;
        if (e < E) {
            int u = ei0[e], v = ei1[e];
            int p = atomicAdd(&cursor[u], 1);
            desc[p] = make_int2(offs[v], deg[v]);
            nbrrank[p] = rank[v];
        }
    }
}

// ---- node5: 2-path accumulation; block per row; flat chains via descriptors ----
__global__ void paths_row_kernel(const int* __restrict__ idx_list, const int* __restrict__ offs,
                                 const int2* __restrict__ desc, const int* __restrict__ nbrrank,
                                 float* __restrict__ ung, int kN) {
    extern __shared__ float row[];              // kN+1 floats; then toff[256], tlen[256]
    int* toff = (int*)(row + kN + 1);
    int* tlen = toff + 256;
    int tid = threadIdx.x;
    float4* row4 = (float4*)row;
    float4 z4 = make_float4(0.f, 0.f, 0.f, 0.f);
    for (int i = tid; i < (kN >> 2); i += 256) row4[i] = z4;   // discard slot not zeroed (unused)
    __syncthreads();
    int u = idx_list[blockIdx.x];
    int s0 = offs[u], s1 = offs[u + 1];
    int nf = s1 - s0;
    int hw = tid >> 5;                          // half-wave 0..7
    int hl = tid & 31;
    for (int fb = 0; fb < nf; fb += 256) {
        int nt = min(256, nf - fb);
        if (tid < nt) {
            int2 dd = desc[s0 + fb + tid];      // coalesced 8B descriptor stage
            toff[tid] = dd.x; tlen[tid] = dd.y;
        }
        __syncthreads();
        for (int f = hw; f < nt; f += 8) {      // half-wave per first-hop segment
            int t0 = toff[f], L = tlen[f];
            for (int q = hl; q < L; q += 32)
                atomicAdd(&row[nbrrank[t0 + q]], 1.0f);   // 1-deep chain
        }
        __syncthreads();
    }
    float4* dst = (float4*)(ung + (size_t)blockIdx.x * kN);
    for (int i = tid; i < (kN >> 2); i += 256) dst[i] = row4[i];
}

extern "C" void kernel_launch(void* const* d_in, const int* in_sizes, int n_in,
                              void* d_out, int out_size, void* d_ws, size_t ws_size,
                              hipStream_t stream) {
    const float* h = (const float*)d_in[0];
    const int* ei = (const int*)d_in[1];            // [2,E] flat: ei0 = ei, ei1 = ei+E
    const int* batch = (const int*)d_in[3];
    const float* pw = (const float*)d_in[4];
    const float* pb = (const float*)d_in[5];

    int N = in_sizes[3];        // 8192
    int E = in_sizes[1] / 2;    // 262144
    int kN = N / 2;
    if (kN < 2) kN = 2;

    float* out = (float*)d_out;
    float* out_newh = out;                              // kN*256
    float* out_ung = out_newh + (size_t)kN * 256;       // kN*kN
    float* out_ea = out_ung + (size_t)kN * kN;          // E
    float* out_nb = out_ea + E;                         // kN
    float* out_idx = out_nb + kN;                       // kN

    char* ws = (char*)d_ws;
    u64* keys    = (u64*)(ws + 0);          // 64 KB
    int* rankcnt = (int*)(ws + 65536);      // 32 KB \ zeroed together in
    int* deg     = (int*)(ws + 98304);      // 32 KB / fused_scores
    int* idx_list= (int*)(ws + 131072);     // 16 KB
    float* vals  = (float*)(ws + 147456);   // 16 KB
    int* rank    = (int*)(ws + 163840);     // 32 KB
    int* offs    = (int*)(ws + 196608);     // 32 KB + 4
    int* cursor  = (int*)(ws + 229632);     // 32 KB
    int2* desc   = (int2*)(ws + 262400);    // 2 MB
    int* nbrrank = (int*)(ws + 2359552);    // 1 MB

    // node1: scores + zero(rankcnt,deg) + ones(edge_attr)
    fused_scores<<<(N * 64 + 255) / 256, 256, 0, stream>>>(h, pw, pb, keys, rankcnt,
                                                           (float4*)out_ea, N, E / 4);
    // node2: rank counting (4 elem/thread, LDS 1024-key tiles) + degree histogram
    int nrank = (N >> 10) * (N >> 10);
    int nhist = (E + 1023) / 1024;
    rank_hist<<<nrank + nhist, 256, 0, stream>>>(keys, rankcnt, ei, deg, N, E, nrank);
    // node3: select + scan
    select_scan<<<(N >> 10) + 1, 1024, 0, stream>>>(keys, rankcnt, batch, idx_list, vals,
                                                    rank, out_idx, out_nb, deg, offs,
                                                    cursor, N, kN);
    // node4: new_h + scatter with packed 2-hop descriptors
    newh_scatter<<<(kN >> 2) + (E >> 8), 256, 0, stream>>>(h, idx_list, vals, out_newh,
                                                           ei, ei + E, cursor, offs, deg,
                                                           rank, desc, nbrrank, kN, E);
    // node5: per-row 2-path accumulation
    paths_row_kernel<<<kN, 256, (kN + 1) * 4 + 2048, stream>>>(idx_list, offs, desc,
                                                               nbrrank, out_ung, kN);
}

// Round 10
// 94.178 us; speedup vs baseline: 6.5860x; 1.1439x over previous
//
#include <hip/hip_runtime.h>

// GraphUnetPool: scores = sigmoid(h@w+b); top-k (k=N/2) by exact rank-count;
// new_h = h[idx]*values; un_g = (g@g)[idx][:,idx] via per-row LDS 2-path counting.
// 5 graph nodes: [scores+zero+ones] -> [rank+hist] -> [select+scan] ->
//                [newh+scatter+2hop-desc] -> [paths].

typedef unsigned long long u64;
typedef unsigned int u32;
typedef float f32x4 __attribute__((ext_vector_type(4)));   // native vec for nt-store

__device__ __forceinline__ void nt_store4(float* p, float x, float y, float z, float w) {
    f32x4 v = { x, y, z, w };
    __builtin_nontemporal_store(v, (f32x4*)p);
}

// ---- node1: scores (1 wave/row) + zero rankcnt/deg + edge_attr ones ----
__global__ void fused_scores(const float* __restrict__ h, const float* __restrict__ w,
                             const float* __restrict__ b, u64* __restrict__ keys,
                             int* __restrict__ zerobuf, float* __restrict__ ones_out,
                             int N, int n4) {
    int g = blockIdx.x * blockDim.x + threadIdx.x;
    if (g < 2 * N) zerobuf[g] = 0;              // rankcnt (N) + deg (N), adjacent
    if (g < n4) nt_store4(ones_out + (size_t)g * 4, 1.f, 1.f, 1.f, 1.f);
    int wave = g >> 6;
    int lane = threadIdx.x & 63;
    if (wave >= N) return;
    const float4 a = ((const float4*)(h + (size_t)wave * 256))[lane];
    const float4 c = ((const float4*)w)[lane];
    float s = a.x * c.x + a.y * c.y + a.z * c.z + a.w * c.w;
    #pragma unroll
    for (int off = 32; off; off >>= 1) s += __shfl_xor(s, off);
    if (lane == 0) {
        s += b[0];
        float sc = 1.0f / (1.0f + expf(-s));
        keys[wave] = ((u64)__float_as_uint(sc) << 32) | (u32)(~wave);  // ties: lower idx
    }
}

// ---- node2: rank = #{j: key_j > key_i} (R5 shape: 1024-key LDS tiles,
//             1 element/thread, 256 blocks) + degree hist ----
__global__ void rank_hist(const u64* __restrict__ keys, int* __restrict__ rankcnt,
                          const int* __restrict__ ei0, int* __restrict__ deg,
                          int N, int E, int nrank) {
    __shared__ u64 lk[1024];
    int b = blockIdx.x, tid = threadIdx.x;
    if (b < nrank) {
        int ngroups = N >> 8;                   // element groups of 256
        int chunk = b / ngroups;                // 1024-key chunks
        int elg = b % ngroups;
        int base = chunk << 10;
        #pragma unroll
        for (int j = 0; j < 4; ++j) lk[tid + (j << 8)] = keys[base + tid + (j << 8)];
        __syncthreads();
        int el = (elg << 8) + tid;
        u64 mk = keys[el];
        int cnt = 0;
        #pragma unroll 16
        for (int i = 0; i < 1024; ++i) cnt += (lk[i] > mk) ? 1 : 0;
        atomicAdd(&rankcnt[el], cnt);
    } else {
        int e0 = ((b - nrank) << 10) + tid;     // 4 edges/thread
        #pragma unroll
        for (int j = 0; j < 4; ++j) {
            int e = e0 + (j << 8);
            if (e < E) atomicAdd(&deg[ei0[e]], 1);
        }
    }
}

// ---- node3: select (rank scatter, outputs idx/batch) + CSR exclusive scan ----
__global__ void select_scan(const u64* __restrict__ keys, const int* __restrict__ rankcnt,
                            const int* __restrict__ batch, int* __restrict__ idx_list,
                            float* __restrict__ val_list, int* __restrict__ rank,
                            float* __restrict__ out_idx, float* __restrict__ out_batch,
                            const int* __restrict__ deg, int* __restrict__ offs,
                            int* __restrict__ cursor, int N, int kN) {
    __shared__ int part[1024];
    int b = blockIdx.x, t = threadIdx.x;
    int nsel = N >> 10;                         // select blocks (1024 thr each)
    if (b < nsel) {
        int i = (b << 10) + t;
        int r = rankcnt[i];
        rank[i] = (r < kN) ? r : kN;            // kN = discard slot
        if (r < kN) {
            idx_list[r] = i;
            val_list[r] = __uint_as_float((u32)(keys[i] >> 32));
            out_idx[r] = (float)i;
            out_batch[r] = (float)batch[i];
        }
    } else {
        int per = N >> 10;                      // 8 per thread
        int base = t * per;
        int loc[8];
        int s = 0;
        #pragma unroll
        for (int j = 0; j < 8; ++j) { if (j < per) { loc[j] = s; s += deg[base + j]; } }
        part[t] = s;
        __syncthreads();
        for (int d = 1; d < 1024; d <<= 1) {
            int v = (t >= d) ? part[t - d] : 0;
            __syncthreads();
            part[t] += v;
            __syncthreads();
        }
        int excl = (t == 0) ? 0 : part[t - 1];
        #pragma unroll
        for (int j = 0; j < 8; ++j) {
            if (j < per) { int o = excl + loc[j]; offs[base + j] = o; cursor[base + j] = o; }
        }
        if (t == 1023) offs[N] = part[1023];
    }
}

// ---- node4: new_h + scatter with packed 2-hop descriptors ----
// Slot p (edge u->v): desc[p] = {offs[v], deg[v]}, nbrrank[p] = rank[v].
__global__ void newh_scatter(const float* __restrict__ h, const int* __restrict__ idx_list,
                             const float* __restrict__ val_list, float* __restrict__ out_newh,
                             const int* __restrict__ ei0, const int* __restrict__ ei1,
                             int* __restrict__ cursor, const int* __restrict__ offs,
                             const int* __restrict__ deg, const int* __restrict__ rank,
                             int2* __restrict__ desc, int* __restrict__ nbrrank,
                             int kN, int E) {
    int b = blockIdx.x, tid = threadIdx.x;
    int nnewh = kN >> 2;                        // 4 waves/block
    if (b < nnewh) {
        int wave = (b << 2) + (tid >> 6);
        int lane = tid & 63;
        int i = idx_list[wave];
        float v = val_list[wave];
        float4 a = ((const float4*)(h + (size_t)i * 256))[lane];
        nt_store4(out_newh + (size_t)wave * 256 + lane * 4,
                  a.x * v, a.y * v, a.z * v, a.w * v);
    } else {
        int e = ((b - nnewh) << 8) + tid;
        if (e < E) {
            int u = ei0[e], v = ei1[e];
            int p = atomicAdd(&cursor[u], 1);
            desc[p] = make_int2(offs[v], deg[v]);
            nbrrank[p] = rank[v];
        }
    }
}

// ---- node5: 2-path accumulation; block per row; flat chains via descriptors ----
__global__ void paths_row_kernel(const int* __restrict__ idx_list, const int* __restrict__ offs,
                                 const int2* __restrict__ desc, const int* __restrict__ nbrrank,
                                 float* __restrict__ ung, int kN) {
    extern __shared__ float row[];              // kN+1 floats; then toff[256], tlen[256]
    int* toff = (int*)(row + kN + 1);
    int* tlen = toff + 256;
    int tid = threadIdx.x;
    float4* row4 = (float4*)row;
    float4 z4 = make_float4(0.f, 0.f, 0.f, 0.f);
    for (int i = tid; i < (kN >> 2); i += 256) row4[i] = z4;   // discard slot unused
    __syncthreads();
    int u = idx_list[blockIdx.x];
    int s0 = offs[u], s1 = offs[u + 1];
    int nf = s1 - s0;
    int hw = tid >> 5;                          // half-wave 0..7
    int hl = tid & 31;
    for (int fb = 0; fb < nf; fb += 256) {
        int nt = min(256, nf - fb);
        if (tid < nt) {
            int2 dd = desc[s0 + fb + tid];      // coalesced 8B descriptor stage
            toff[tid] = dd.x; tlen[tid] = dd.y;
        }
        __syncthreads();
        for (int f = hw; f < nt; f += 8) {      // half-wave per first-hop segment
            int t0 = toff[f], L = tlen[f];
            for (int q = hl; q < L; q += 32)
                atomicAdd(&row[nbrrank[t0 + q]], 1.0f);   // 1-deep chain
        }
        __syncthreads();
    }
    float* dst = ung + (size_t)blockIdx.x * kN;
    for (int i = tid; i < (kN >> 2); i += 256) {
        float4 v = row4[i];
        nt_store4(dst + (size_t)i * 4, v.x, v.y, v.z, v.w);   // don't evict gather set
    }
}

extern "C" void kernel_launch(void* const* d_in, const int* in_sizes, int n_in,
                              void* d_out, int out_size, void* d_ws, size_t ws_size,
                              hipStream_t stream) {
    const float* h = (const float*)d_in[0];
    const int* ei = (const int*)d_in[1];            // [2,E] flat: ei0 = ei, ei1 = ei+E
    const int* batch = (const int*)d_in[3];
    const float* pw = (const float*)d_in[4];
    const float* pb = (const float*)d_in[5];

    int N = in_sizes[3];        // 8192
    int E = in_sizes[1] / 2;    // 262144
    int kN = N / 2;
    if (kN < 2) kN = 2;

    float* out = (float*)d_out;
    float* out_newh = out;                              // kN*256
    float* out_ung = out_newh + (size_t)kN * 256;       // kN*kN
    float* out_ea = out_ung + (size_t)kN * kN;          // E
    float* out_nb = out_ea + E;                         // kN
    float* out_idx = out_nb + kN;                       // kN

    char* ws = (char*)d_ws;
    u64* keys    = (u64*)(ws + 0);          // 64 KB
    int* rankcnt = (int*)(ws + 65536);      // 32 KB \ zeroed together in
    int* deg     = (int*)(ws + 98304);      // 32 KB / fused_scores
    int* idx_list= (int*)(ws + 131072);     // 16 KB
    float* vals  = (float*)(ws + 147456);   // 16 KB
    int* rank    = (int*)(ws + 163840);     // 32 KB
    int* offs    = (int*)(ws + 196608);     // 32 KB + 4
    int* cursor  = (int*)(ws + 229632);     // 32 KB
    int2* desc   = (int2*)(ws + 262400);    // 2 MB
    int* nbrrank = (int*)(ws + 2359552);    // 1 MB

    // node1: scores + zero(rankcnt,deg) + ones(edge_attr)
    fused_scores<<<(N * 64 + 255) / 256, 256, 0, stream>>>(h, pw, pb, keys, rankcnt,
                                                           out_ea, N, E / 4);
    // node2: rank counting (1024-key LDS tiles, 1 elem/thread) + degree histogram
    int nrank = (N >> 10) * (N >> 8);
    int nhist = (E + 1023) / 1024;
    rank_hist<<<nrank + nhist, 256, 0, stream>>>(keys, rankcnt, ei, deg, N, E, nrank);
    // node3: select + scan
    select_scan<<<(N >> 10) + 1, 1024, 0, stream>>>(keys, rankcnt, batch, idx_list, vals,
                                                    rank, out_idx, out_nb, deg, offs,
                                                    cursor, N, kN);
    // node4: new_h + scatter with packed 2-hop descriptors
    newh_scatter<<<(kN >> 2) + (E >> 8), 256, 0, stream>>>(h, idx_list, vals, out_newh,
                                                           ei, ei + E, cursor, offs, deg,
                                                           rank, desc, nbrrank, kN, E);
    // node5: per-row 2-path accumulation
    paths_row_kernel<<<kN, 256, (kN + 1) * 4 + 2048, stream>>>(idx_list, offs, desc,
                                                               nbrrank, out_ung, kN);
}